// Round 12
// baseline (170.279 us; speedup 1.0000x reference)
//
#include <hip/hip_runtime.h>
#include <hip/hip_bf16.h>

#define NEG_SLOPE 0.2f
#define LN_EPS 1e-5f
#define D 64          // Din == Dout == 64
// NOTE: u32 record packing {src:16|dst:16} requires N <= 65536 (problem: N=50000)
#define BSH 6         // 64 dst-nodes per bucket
#define BNODES 64
#define NBMAX 1024    // dst-buckets (N <= 65536)
#define BCAP 1792     // records per dst-bucket (avg 1280 for N=50k,E=1M; +14 sigma)
#define SSH 8         // 256 srcs per src-bucket
#define NSBMAX 256    // src-buckets (N <= 65536)
#define SCAP 6144     // records per src-bucket (avg 5102; +14 sigma)
#define OVFCAP 65536  // overflow list capacity (safety; normally 0 used)

typedef unsigned long long u64;
typedef unsigned int u32;

// ---------------------------------------------------------------------------
// Kernel 1: hW = h @ W^T   (N x 64), plus s1[i] = hW[i].a1, s2[i] = hW[i].a2
// Lane j holds W row j in 64 VGPRs; node index readfirstlane'd so h-row
// loads are wave-uniform (scalar pipe); 64 pure FMAs on 4 acc chains.
// ---------------------------------------------------------------------------
__global__ void __launch_bounds__(256, 4)
k_hw_scores(const float* __restrict__ h,
            const float* __restrict__ W,
            const float* __restrict__ a,
            float* __restrict__ hW,
            float* __restrict__ s1,
            float* __restrict__ s2,
            int N) {
    const int lane = threadIdx.x & 63;
    const int wid  = threadIdx.x >> 6;
    const int wavesPerBlock = blockDim.x >> 6;
    const int nWaves = gridDim.x * wavesPerBlock;

    float wcol[D];
    {
        const float4* wr = (const float4*)(W + (size_t)lane * D);
        #pragma unroll
        for (int q = 0; q < D / 4; ++q) {
            float4 w4 = wr[q];
            wcol[q * 4 + 0] = w4.x; wcol[q * 4 + 1] = w4.y;
            wcol[q * 4 + 2] = w4.z; wcol[q * 4 + 3] = w4.w;
        }
    }
    const float a1l = a[lane];
    const float a2l = a[D + lane];

    for (int i = blockIdx.x * wavesPerBlock + wid; i < N; i += nWaves) {
        const int iu = __builtin_amdgcn_readfirstlane(i);
        const float* hr = h + (size_t)iu * D;   // wave-uniform -> scalar loads

        float acc0 = 0.f, acc1 = 0.f, acc2 = 0.f, acc3 = 0.f;
        #pragma unroll
        for (int k = 0; k < D; k += 4) {
            acc0 = fmaf(hr[k + 0], wcol[k + 0], acc0);
            acc1 = fmaf(hr[k + 1], wcol[k + 1], acc1);
            acc2 = fmaf(hr[k + 2], wcol[k + 2], acc2);
            acc3 = fmaf(hr[k + 3], wcol[k + 3], acc3);
        }
        float c = (acc0 + acc1) + (acc2 + acc3);
        hW[(size_t)iu * D + lane] = c;

        float p1 = c * a1l;
        float p2 = c * a2l;
        #pragma unroll
        for (int off = 32; off > 0; off >>= 1) {
            p1 += __shfl_xor(p1, off, 64);
            p2 += __shfl_xor(p2, off, 64);
        }
        if (lane == 0) { s1[iu] = p1; s2[iu] = p2; }
    }
}

__device__ __forceinline__ float edge_ex(float v1, float v2) {
    float x = v1 + v2;
    float e = x > 0.f ? x : NEG_SLOPE * x;
    return expf(fminf(e, 60.f));   // softmax shift-invariant; clamp for safety
}

// ---------------------------------------------------------------------------
// Kernel 2: edge pass, dual binning. No fp atomics, 4B records.
//  dst-copy: rec = src | (dstl<<16), bucket d>>6
//  src-copy: rec = src | (dst<<16),  bucket s>>8  (for denom reduction)
// TPB=1024/EPT=4 (4096 edges/block) — R8-measured config (512 split
// regressed in R9: cost is not wave-count-bound).
// ---------------------------------------------------------------------------
__global__ void __launch_bounds__(1024)
k_bin(const int* __restrict__ src,
      const int* __restrict__ dst,
      const float* __restrict__ s1,
      const float* __restrict__ s2,
      float* __restrict__ denom,       // only overflow path writes (atomic)
      int* __restrict__ dcnt_g,        // [NBMAX]  (zeroed)
      u32* __restrict__ drecs,         // [nb * BCAP]
      int* __restrict__ scnt_g,        // [NSBMAX] (zeroed)
      u32* __restrict__ srecs,         // [nsb * SCAP]
      u32* __restrict__ ovf_rec,       // [OVFCAP]
      int* __restrict__ ovf_dst,       // [OVFCAP]
      int* __restrict__ ovf_n,         // scalar (zeroed)
      int E, int nb, int nsb) {
    const int TPB = 1024, EPT = 4;     // 4096 edges per block
    __shared__ int lcnt[NBMAX], lbase[NBMAX], lfill[NBMAX];
    __shared__ int scnt[NSBMAX], sbase[NSBMAX], sfill[NSBMAX];

    const int chunk = blockIdx.x * (TPB * EPT);
    for (int i = threadIdx.x; i < nb; i += TPB)  { lcnt[i] = 0; lfill[i] = 0; }
    for (int i = threadIdx.x; i < nsb; i += TPB) { scnt[i] = 0; sfill[i] = 0; }
    __syncthreads();

    int sv[EPT], dv[EPT];
    const int e0 = chunk + threadIdx.x * EPT;
    if (e0 + EPT <= E) {
        int4 s4 = *(const int4*)(src + e0);
        int4 d4 = *(const int4*)(dst + e0);
        sv[0] = s4.x; sv[1] = s4.y; sv[2] = s4.z; sv[3] = s4.w;
        dv[0] = d4.x; dv[1] = d4.y; dv[2] = d4.z; dv[3] = d4.w;
    } else {
        #pragma unroll
        for (int j = 0; j < EPT; ++j) {
            int i = e0 + j;
            sv[j] = (i < E) ? src[i] : 0;
            dv[j] = (i < E) ? dst[i] : -1;
        }
    }

    #pragma unroll
    for (int j = 0; j < EPT; ++j) {
        if (dv[j] >= 0) {
            atomicAdd(&lcnt[dv[j] >> BSH], 1);
            atomicAdd(&scnt[sv[j] >> SSH], 1);
        }
    }
    __syncthreads();

    for (int b = threadIdx.x; b < nb; b += TPB) {
        int l = lcnt[b];
        if (l) lbase[b] = atomicAdd(&dcnt_g[b], l);
    }
    for (int b = threadIdx.x; b < nsb; b += TPB) {
        int l = scnt[b];
        if (l) sbase[b] = atomicAdd(&scnt_g[b], l);
    }
    __syncthreads();

    #pragma unroll
    for (int j = 0; j < EPT; ++j) {
        int d_ = dv[j];
        if (d_ < 0) continue;
        int s = sv[j];

        // dst-binned record (for aggregation)
        int b = d_ >> BSH;
        u32 drec = (u32)s | ((u32)(d_ & (BNODES - 1)) << 16);
        int r = lbase[b] + atomicAdd(&lfill[b], 1);
        if (r < BCAP) {
            drecs[(size_t)b * BCAP + r] = drec;
        } else {
            int o = atomicAdd(ovf_n, 1);
            if (o < OVFCAP) { ovf_rec[o] = drec; ovf_dst[o] = d_; }
        }

        // src-binned record (for denom)
        int sb = s >> SSH;
        u32 srec = (u32)s | ((u32)d_ << 16);
        int rs = sbase[sb] + atomicAdd(&sfill[sb], 1);
        if (rs < SCAP) {
            srecs[(size_t)sb * SCAP + rs] = srec;
        } else {
            // rare fallback: contribute to denom directly
            atomicAdd(&denom[s], edge_ex(s1[s], s2[d_]));
        }
    }
}

// ---------------------------------------------------------------------------
// Kernel 2b: denom reduction. One block per src-bucket (256 srcs).
// LDS fp32 accumulation -> single contiguous global write.
// ---------------------------------------------------------------------------
__global__ void __launch_bounds__(512)
k_denom(const u32* __restrict__ srecs,
        const int* __restrict__ scnt_g,
        const float* __restrict__ s1,
        const float* __restrict__ s2,
        float* __restrict__ denom,
        int N) {
    __shared__ float acc[256];
    const int b = blockIdx.x;
    const int tid = threadIdx.x;
    if (tid < 256) acc[tid] = 0.f;
    __syncthreads();

    const int total = min(scnt_g[b], SCAP);
    const u32* base = srecs + (size_t)b * SCAP;
    for (int i = tid; i < total; i += 512) {
        u32 r = base[i];
        int s = r & 0xFFFF;
        int d = r >> 16;
        atomicAdd(&acc[s & 255], edge_ex(s1[s], s2[d]));
    }
    __syncthreads();

    if (tid < 256) {
        int g = (b << SSH) + tid;
        if (g < N) denom[g] += acc[tid];
    }
}

// ---------------------------------------------------------------------------
// Kernel 3: one block (512 thr, 8 waves) per 64-node dst-bucket.
// 782 blocks (~3/CU, balanced) vs 391x1024 (1.5/CU, imbalanced).
// Stage u32 records, recompute ex, group by local dst in LDS, aggregate
// with 16-edges-in-flight (4x unrolled, 4 slots) float4 gathers, then
// residual + LN.  g = lane>>4 (edge slot), li = lane&15 (col/4).
// ---------------------------------------------------------------------------
__global__ void __launch_bounds__(512)
k_bucket_agg(const u32* __restrict__ drecs,
             const int* __restrict__ dcnt_g,
             const float* __restrict__ s1,
             const float* __restrict__ s2,
             const float* __restrict__ denom,
             const float* __restrict__ hW,
             const float* __restrict__ gamma,
             const float* __restrict__ beta,
             const u32* __restrict__ ovf_rec,
             const int* __restrict__ ovf_dst,
             const int* __restrict__ ovf_n_p,
             float* __restrict__ out,
             int N) {
    __shared__ u64 ro[BCAP];          // {att_bits:32 | rec:32}
    __shared__ float s2l[BNODES];
    __shared__ int hh[BNODES], oo[BNODES], cc[BNODES];

    const int b    = blockIdx.x;
    const int tid  = threadIdx.x;
    const int lane = tid & 63;
    const int wid  = tid >> 6;        // 8 waves
    const int g    = lane >> 4;       // edge-slot group 0..3
    const int li   = lane & 15;       // column quad 0..15
    const int node0 = b << BSH;
    const int nn    = min(BNODES, N - node0);
    const int total = min(dcnt_g[b], BCAP);

    if (tid < nn) s2l[tid] = s2[node0 + tid];
    if (tid < BNODES) hh[tid] = 0;
    __syncthreads();

    // ---- stage + compute att ----
    u64 rr[4]; bool valid[4];
    const u32* base = drecs + (size_t)b * BCAP;
    #pragma unroll
    for (int q = 0; q < 4; ++q) {
        int idx = tid + q * 512;
        valid[q] = idx < total;
        u32 r = valid[q] ? base[idx] : 0u;
        if (valid[q]) {
            int s  = r & 0xFFFF;
            int dl = (r >> 16) & (BNODES - 1);
            float att = edge_ex(s1[s], s2l[dl]) / denom[s];
            rr[q] = ((u64)__float_as_uint(att) << 32) | (u64)r;
            atomicAdd(&hh[dl], 1);
        } else rr[q] = 0;
    }
    __syncthreads();

    // ---- exclusive scan over 64 counters ----
    if (tid < BNODES) oo[tid] = hh[tid];
    __syncthreads();
    for (int off = 1; off < BNODES; off <<= 1) {
        int t = 0;
        if (tid < BNODES && tid >= off) t = oo[tid - off];
        __syncthreads();
        if (tid < BNODES) oo[tid] += t;
        __syncthreads();
    }
    if (tid < BNODES) { int e_ = oo[tid] - hh[tid]; oo[tid] = e_; cc[tid] = e_; }
    __syncthreads();

    // ---- scatter into dst-grouped LDS buffer ----
    #pragma unroll
    for (int q = 0; q < 4; ++q) if (valid[q])
        ro[atomicAdd(&cc[((u32)rr[q] >> 16) & (BNODES - 1)], 1)] = rr[q];
    __syncthreads();

    int ovn = *ovf_n_p;
    if (ovn > OVFCAP) ovn = OVFCAP;

    // ---- aggregate + residual + LayerNorm; wave owns nodes wid*8..wid*8+7 ----
    #pragma unroll
    for (int k = 0; k < 8; ++k) {
        int nl = (wid << 3) + k;
        if (nl >= nn) break;
        int beg = oo[nl], end = cc[nl];

        float ax = 0.f, ay = 0.f, az = 0.f, aw = 0.f;
        // 4x unrolled: 4 independent gather slots in flight per iteration
        for (int p = beg; p < end; p += 16) {
            float at0 = 0.f, at1 = 0.f, at2 = 0.f, at3 = 0.f;
            int s0 = 0, s1i = 0, s2i = 0, s3 = 0;
            int i0 = p + g, i1 = p + 4 + g, i2 = p + 8 + g, i3 = p + 12 + g;
            if (i0 < end) { u64 r2 = ro[i0]; s0  = (u32)r2 & 0xFFFF; at0 = __uint_as_float((u32)(r2 >> 32)); }
            if (i1 < end) { u64 r2 = ro[i1]; s1i = (u32)r2 & 0xFFFF; at1 = __uint_as_float((u32)(r2 >> 32)); }
            if (i2 < end) { u64 r2 = ro[i2]; s2i = (u32)r2 & 0xFFFF; at2 = __uint_as_float((u32)(r2 >> 32)); }
            if (i3 < end) { u64 r2 = ro[i3]; s3  = (u32)r2 & 0xFFFF; at3 = __uint_as_float((u32)(r2 >> 32)); }
            const float4 v0 = *(const float4*)(hW + (size_t)s0  * D + li * 4);
            const float4 v1 = *(const float4*)(hW + (size_t)s1i * D + li * 4);
            const float4 v2 = *(const float4*)(hW + (size_t)s2i * D + li * 4);
            const float4 v3 = *(const float4*)(hW + (size_t)s3  * D + li * 4);
            ax = fmaf(at0, v0.x, ax); ay = fmaf(at0, v0.y, ay);
            az = fmaf(at0, v0.z, az); aw = fmaf(at0, v0.w, aw);
            ax = fmaf(at1, v1.x, ax); ay = fmaf(at1, v1.y, ay);
            az = fmaf(at1, v1.z, az); aw = fmaf(at1, v1.w, aw);
            ax = fmaf(at2, v2.x, ax); ay = fmaf(at2, v2.y, ay);
            az = fmaf(at2, v2.z, az); aw = fmaf(at2, v2.w, aw);
            ax = fmaf(at3, v3.x, ax); ay = fmaf(at3, v3.y, ay);
            az = fmaf(at3, v3.z, az); aw = fmaf(at3, v3.w, aw);
        }

        // overflow safety path (normally ovn == 0); add on group 0 only
        for (int r = 0; r < ovn; ++r) {
            if (ovf_dst[r] != node0 + nl) continue;
            if (g == 0) {
                u32 r2 = ovf_rec[r];
                int s = r2 & 0xFFFF;
                float att = edge_ex(s1[s], s2l[nl]) / denom[s];
                const float4 v = *(const float4*)(hW + (size_t)s * D + li * 4);
                ax = fmaf(att, v.x, ax); ay = fmaf(att, v.y, ay);
                az = fmaf(att, v.z, az); aw = fmaf(att, v.w, aw);
            }
        }

        // reduce across the 4 edge-slot groups
        ax += __shfl_xor(ax, 16, 64); ax += __shfl_xor(ax, 32, 64);
        ay += __shfl_xor(ay, 16, 64); ay += __shfl_xor(ay, 32, 64);
        az += __shfl_xor(az, 16, 64); az += __shfl_xor(az, 32, 64);
        aw += __shfl_xor(aw, 16, 64); aw += __shfl_xor(aw, 32, 64);

        // residual
        const float4 hv = *(const float4*)(hW + (size_t)(node0 + nl) * D + li * 4);
        float x0 = hv.x + ax, x1 = hv.y + ay, x2 = hv.z + az, x3 = hv.w + aw;

        // LayerNorm over 64 cols
        float sm = x0 + x1 + x2 + x3;
        sm += __shfl_xor(sm, 1, 64); sm += __shfl_xor(sm, 2, 64);
        sm += __shfl_xor(sm, 4, 64); sm += __shfl_xor(sm, 8, 64);
        float mu = sm * (1.f / D);
        float d0 = x0 - mu, d1 = x1 - mu, d2 = x2 - mu, d3 = x3 - mu;
        float vv = d0 * d0 + d1 * d1 + d2 * d2 + d3 * d3;
        vv += __shfl_xor(vv, 1, 64); vv += __shfl_xor(vv, 2, 64);
        vv += __shfl_xor(vv, 4, 64); vv += __shfl_xor(vv, 8, 64);
        float inv = rsqrtf(vv * (1.f / D) + LN_EPS);

        if (g == 0) {
            const float4 gm = *(const float4*)(gamma + li * 4);
            const float4 bt = *(const float4*)(beta + li * 4);
            float4 o;
            o.x = d0 * inv * gm.x + bt.x;
            o.y = d1 * inv * gm.y + bt.y;
            o.z = d2 * inv * gm.z + bt.z;
            o.w = d3 * inv * gm.w + bt.w;
            *(float4*)(out + (size_t)(node0 + nl) * D + li * 4) = o;
        }
    }
}

// ---------------------------------------------------------------------------
static inline size_t align256(size_t x) { return (x + 255) & ~size_t(255); }

extern "C" void kernel_launch(void* const* d_in, const int* in_sizes, int n_in,
                              void* d_out, int out_size, void* d_ws, size_t ws_size,
                              hipStream_t stream) {
    const float* h    = (const float*)d_in[0];
    const int*   ei   = (const int*)d_in[1];
    const float* W    = (const float*)d_in[2];
    const float* a    = (const float*)d_in[3];
    const float* lng  = (const float*)d_in[4];
    const float* lnb  = (const float*)d_in[5];
    float* out = (float*)d_out;

    const int N = in_sizes[0] / D;
    const int E = in_sizes[1] / 2;
    const int* src = ei;        // edge_index[0]
    const int* dst = ei + E;    // edge_index[1]
    const int nb  = (N + BNODES - 1) >> BSH;   // dst-buckets (64-node)
    const int nsb = (N + 255) >> SSH;          // src-buckets

    // workspace layout
    char* ws = (char*)d_ws;
    size_t off = 0;
    float* hW      = (float*)(ws + off); off += align256(sizeof(float) * (size_t)N * D);
    float* s1      = (float*)(ws + off); off += align256(sizeof(float) * (size_t)N);
    float* s2      = (float*)(ws + off); off += align256(sizeof(float) * (size_t)N);
    u32*   drecs   = (u32*)  (ws + off); off += align256(sizeof(u32) * (size_t)nb * BCAP);
    u32*   srecs   = (u32*)  (ws + off); off += align256(sizeof(u32) * (size_t)nsb * SCAP);
    u32*   ovf_rec = (u32*)  (ws + off); off += align256(sizeof(u32) * (size_t)OVFCAP);
    int*   ovf_dst = (int*)  (ws + off); off += align256(sizeof(int) * (size_t)OVFCAP);
    // zero-initialized tail: denom, dcnt_g, scnt_g, ovf_n (one memset)
    size_t zero_off = off;
    float* denom   = (float*)(ws + off); off += align256(sizeof(float) * (size_t)N);
    int*   dcnt_g  = (int*)  (ws + off); off += align256(sizeof(int) * (size_t)NBMAX);
    int*   scnt_g  = (int*)  (ws + off); off += align256(sizeof(int) * (size_t)NSBMAX);
    int*   ovf_n   = (int*)  (ws + off); off += align256(sizeof(int));
    size_t zero_bytes = off - zero_off;

    hipMemsetAsync(ws + zero_off, 0, zero_bytes, stream);

    // K1: hW + attention scores
    k_hw_scores<<<dim3(1024), dim3(256), 0, stream>>>(h, W, a, hW, s1, s2, N);

    // K2: dual binning (4096 edges/block, 1024 thr — R8 config)
    k_bin<<<dim3((E + 4095) / 4096), dim3(1024), 0, stream>>>(
        src, dst, s1, s2, denom, dcnt_g, drecs, scnt_g, srecs,
        ovf_rec, ovf_dst, ovf_n, E, nb, nsb);

    // K2b: denom reduction per src-bucket
    k_denom<<<dim3(nsb), dim3(512), 0, stream>>>(srecs, scnt_g, s1, s2, denom, N);

    // K3: fused bucket sort + aggregate + residual + LayerNorm (64-node buckets)
    k_bucket_agg<<<dim3(nb), dim3(512), 0, stream>>>(
        drecs, dcnt_g, s1, s2, denom, hW, lng, lnb,
        ovf_rec, ovf_dst, ovf_n, out, N);
}

// Round 13
// 164.287 us; speedup vs baseline: 1.0365x; 1.0365x over previous
//
#include <hip/hip_runtime.h>
#include <hip/hip_bf16.h>

#define NEG_SLOPE 0.2f
#define LN_EPS 1e-5f
#define D 64          // Din == Dout == 64
// NOTE: u32 record packing {src:16|dst:16} requires N <= 65536 (problem: N=50000)
#define BSH 6         // 64 dst-nodes per bucket
#define BNODES 64
#define NBMAX 1024    // dst-buckets (N <= 65536)
#define BCAP 1792     // records per dst-bucket (avg 1280 for N=50k,E=1M; +14 sigma)
#define SSH 8         // 256 srcs per src-bucket
#define NSBMAX 256    // src-buckets (N <= 65536)
#define SCAP 6144     // records per src-bucket (avg 5102; +14 sigma)
#define OVFCAP 65536  // overflow list capacity (safety; normally 0 used)

typedef unsigned long long u64;
typedef unsigned int u32;
typedef unsigned short u16;

// bf16 pack (RNE) / unpack helpers
__device__ __forceinline__ u16 f2bf(float f) {
    u32 u = __float_as_uint(f);
    return (u16)((u + 0x7FFFu + ((u >> 16) & 1u)) >> 16);
}
__device__ __forceinline__ float bf_lo(u32 p) { return __uint_as_float(p << 16); }
__device__ __forceinline__ float bf_hi(u32 p) { return __uint_as_float(p & 0xFFFF0000u); }

// ---------------------------------------------------------------------------
// Kernel 1: hW = h @ W^T  (fp32 + bf16 replica), s1/s2 attention scores.
// Lane j holds W row j in 64 VGPRs; node index readfirstlane'd so h-row
// loads are wave-uniform (scalar pipe); 64 pure FMAs on 4 acc chains.
// ---------------------------------------------------------------------------
__global__ void __launch_bounds__(256, 4)
k_hw_scores(const float* __restrict__ h,
            const float* __restrict__ W,
            const float* __restrict__ a,
            float* __restrict__ hW,
            u16* __restrict__ hWb,
            float* __restrict__ s1,
            float* __restrict__ s2,
            int N) {
    const int lane = threadIdx.x & 63;
    const int wid  = threadIdx.x >> 6;
    const int wavesPerBlock = blockDim.x >> 6;
    const int nWaves = gridDim.x * wavesPerBlock;

    float wcol[D];
    {
        const float4* wr = (const float4*)(W + (size_t)lane * D);
        #pragma unroll
        for (int q = 0; q < D / 4; ++q) {
            float4 w4 = wr[q];
            wcol[q * 4 + 0] = w4.x; wcol[q * 4 + 1] = w4.y;
            wcol[q * 4 + 2] = w4.z; wcol[q * 4 + 3] = w4.w;
        }
    }
    const float a1l = a[lane];
    const float a2l = a[D + lane];

    for (int i = blockIdx.x * wavesPerBlock + wid; i < N; i += nWaves) {
        const int iu = __builtin_amdgcn_readfirstlane(i);
        const float* hr = h + (size_t)iu * D;   // wave-uniform -> scalar loads

        float acc0 = 0.f, acc1 = 0.f, acc2 = 0.f, acc3 = 0.f;
        #pragma unroll
        for (int k = 0; k < D; k += 4) {
            acc0 = fmaf(hr[k + 0], wcol[k + 0], acc0);
            acc1 = fmaf(hr[k + 1], wcol[k + 1], acc1);
            acc2 = fmaf(hr[k + 2], wcol[k + 2], acc2);
            acc3 = fmaf(hr[k + 3], wcol[k + 3], acc3);
        }
        float c = (acc0 + acc1) + (acc2 + acc3);
        hW[(size_t)iu * D + lane] = c;
        hWb[(size_t)iu * D + lane] = f2bf(c);

        float p1 = c * a1l;
        float p2 = c * a2l;
        #pragma unroll
        for (int off = 32; off > 0; off >>= 1) {
            p1 += __shfl_xor(p1, off, 64);
            p2 += __shfl_xor(p2, off, 64);
        }
        if (lane == 0) { s1[iu] = p1; s2[iu] = p2; }
    }
}

__device__ __forceinline__ float edge_ex(float v1, float v2) {
    float x = v1 + v2;
    float e = x > 0.f ? x : NEG_SLOPE * x;
    return expf(fminf(e, 60.f));   // softmax shift-invariant; clamp for safety
}

// ---------------------------------------------------------------------------
// Kernel 2: edge pass, dual binning. No fp atomics, 4B records.
//  dst-copy: rec = src | (dstl<<16), bucket d>>6
//  src-copy: rec = src | (dst<<16),  bucket s>>8  (for denom reduction)
// TPB=1024/EPT=4 (4096 edges/block) — R8-measured config.
// ---------------------------------------------------------------------------
__global__ void __launch_bounds__(1024)
k_bin(const int* __restrict__ src,
      const int* __restrict__ dst,
      const float* __restrict__ s1,
      const float* __restrict__ s2,
      float* __restrict__ denom,       // only overflow path writes (atomic)
      int* __restrict__ dcnt_g,        // [NBMAX]  (zeroed)
      u32* __restrict__ drecs,         // [nb * BCAP]
      int* __restrict__ scnt_g,        // [NSBMAX] (zeroed)
      u32* __restrict__ srecs,         // [nsb * SCAP]
      u32* __restrict__ ovf_rec,       // [OVFCAP]
      int* __restrict__ ovf_dst,       // [OVFCAP]
      int* __restrict__ ovf_n,         // scalar (zeroed)
      int E, int nb, int nsb) {
    const int TPB = 1024, EPT = 4;     // 4096 edges per block
    __shared__ int lcnt[NBMAX], lbase[NBMAX], lfill[NBMAX];
    __shared__ int scnt[NSBMAX], sbase[NSBMAX], sfill[NSBMAX];

    const int chunk = blockIdx.x * (TPB * EPT);
    for (int i = threadIdx.x; i < nb; i += TPB)  { lcnt[i] = 0; lfill[i] = 0; }
    for (int i = threadIdx.x; i < nsb; i += TPB) { scnt[i] = 0; sfill[i] = 0; }
    __syncthreads();

    int sv[EPT], dv[EPT];
    const int e0 = chunk + threadIdx.x * EPT;
    if (e0 + EPT <= E) {
        int4 s4 = *(const int4*)(src + e0);
        int4 d4 = *(const int4*)(dst + e0);
        sv[0] = s4.x; sv[1] = s4.y; sv[2] = s4.z; sv[3] = s4.w;
        dv[0] = d4.x; dv[1] = d4.y; dv[2] = d4.z; dv[3] = d4.w;
    } else {
        #pragma unroll
        for (int j = 0; j < EPT; ++j) {
            int i = e0 + j;
            sv[j] = (i < E) ? src[i] : 0;
            dv[j] = (i < E) ? dst[i] : -1;
        }
    }

    #pragma unroll
    for (int j = 0; j < EPT; ++j) {
        if (dv[j] >= 0) {
            atomicAdd(&lcnt[dv[j] >> BSH], 1);
            atomicAdd(&scnt[sv[j] >> SSH], 1);
        }
    }
    __syncthreads();

    for (int b = threadIdx.x; b < nb; b += TPB) {
        int l = lcnt[b];
        if (l) lbase[b] = atomicAdd(&dcnt_g[b], l);
    }
    for (int b = threadIdx.x; b < nsb; b += TPB) {
        int l = scnt[b];
        if (l) sbase[b] = atomicAdd(&scnt_g[b], l);
    }
    __syncthreads();

    #pragma unroll
    for (int j = 0; j < EPT; ++j) {
        int d_ = dv[j];
        if (d_ < 0) continue;
        int s = sv[j];

        // dst-binned record (for aggregation)
        int b = d_ >> BSH;
        u32 drec = (u32)s | ((u32)(d_ & (BNODES - 1)) << 16);
        int r = lbase[b] + atomicAdd(&lfill[b], 1);
        if (r < BCAP) {
            drecs[(size_t)b * BCAP + r] = drec;
        } else {
            int o = atomicAdd(ovf_n, 1);
            if (o < OVFCAP) { ovf_rec[o] = drec; ovf_dst[o] = d_; }
        }

        // src-binned record (for denom)
        int sb = s >> SSH;
        u32 srec = (u32)s | ((u32)d_ << 16);
        int rs = sbase[sb] + atomicAdd(&sfill[sb], 1);
        if (rs < SCAP) {
            srecs[(size_t)sb * SCAP + rs] = srec;
        } else {
            // rare fallback: contribute to denom directly
            atomicAdd(&denom[s], edge_ex(s1[s], s2[d_]));
        }
    }
}

// ---------------------------------------------------------------------------
// Kernel 2b: denom reduction. One block per src-bucket (256 srcs).
// LDS fp32 accumulation -> single contiguous global write.
// ---------------------------------------------------------------------------
__global__ void __launch_bounds__(512)
k_denom(const u32* __restrict__ srecs,
        const int* __restrict__ scnt_g,
        const float* __restrict__ s1,
        const float* __restrict__ s2,
        float* __restrict__ denom,
        int N) {
    __shared__ float acc[256];
    const int b = blockIdx.x;
    const int tid = threadIdx.x;
    if (tid < 256) acc[tid] = 0.f;
    __syncthreads();

    const int total = min(scnt_g[b], SCAP);
    const u32* base = srecs + (size_t)b * SCAP;
    for (int i = tid; i < total; i += 512) {
        u32 r = base[i];
        int s = r & 0xFFFF;
        int d = r >> 16;
        atomicAdd(&acc[s & 255], edge_ex(s1[s], s2[d]));
    }
    __syncthreads();

    if (tid < 256) {
        int g = (b << SSH) + tid;
        if (g < N) denom[g] += acc[tid];
    }
}

// ---------------------------------------------------------------------------
// Kernel 3: one block (512 thr, 8 waves) per 64-node dst-bucket.
// Stage u32 records, recompute ex, group by local dst in LDS, aggregate
// with 16-edges-in-flight gathers FROM THE BF16 REPLICA (8 B/lane, 2
// lines/row instead of 4 — halves the L2-miss traffic that R8-R12 showed
// to be the invariant floor). Residual + LN stay fp32.
// g = lane>>4 (edge slot), li = lane&15 (col/4).
// ---------------------------------------------------------------------------
__global__ void __launch_bounds__(512)
k_bucket_agg(const u32* __restrict__ drecs,
             const int* __restrict__ dcnt_g,
             const float* __restrict__ s1,
             const float* __restrict__ s2,
             const float* __restrict__ denom,
             const float* __restrict__ hW,
             const u16* __restrict__ hWb,
             const float* __restrict__ gamma,
             const float* __restrict__ beta,
             const u32* __restrict__ ovf_rec,
             const int* __restrict__ ovf_dst,
             const int* __restrict__ ovf_n_p,
             float* __restrict__ out,
             int N) {
    __shared__ u64 ro[BCAP];          // {att_bits:32 | rec:32}
    __shared__ float s2l[BNODES];
    __shared__ int hh[BNODES], oo[BNODES], cc[BNODES];

    const int b    = blockIdx.x;
    const int tid  = threadIdx.x;
    const int lane = tid & 63;
    const int wid  = tid >> 6;        // 8 waves
    const int g    = lane >> 4;       // edge-slot group 0..3
    const int li   = lane & 15;       // column quad 0..15
    const int node0 = b << BSH;
    const int nn    = min(BNODES, N - node0);
    const int total = min(dcnt_g[b], BCAP);

    if (tid < nn) s2l[tid] = s2[node0 + tid];
    if (tid < BNODES) hh[tid] = 0;
    __syncthreads();

    // ---- stage + compute att ----
    u64 rr[4]; bool valid[4];
    const u32* base = drecs + (size_t)b * BCAP;
    #pragma unroll
    for (int q = 0; q < 4; ++q) {
        int idx = tid + q * 512;
        valid[q] = idx < total;
        u32 r = valid[q] ? base[idx] : 0u;
        if (valid[q]) {
            int s  = r & 0xFFFF;
            int dl = (r >> 16) & (BNODES - 1);
            float att = edge_ex(s1[s], s2l[dl]) / denom[s];
            rr[q] = ((u64)__float_as_uint(att) << 32) | (u64)r;
            atomicAdd(&hh[dl], 1);
        } else rr[q] = 0;
    }
    __syncthreads();

    // ---- exclusive scan over 64 counters ----
    if (tid < BNODES) oo[tid] = hh[tid];
    __syncthreads();
    for (int off = 1; off < BNODES; off <<= 1) {
        int t = 0;
        if (tid < BNODES && tid >= off) t = oo[tid - off];
        __syncthreads();
        if (tid < BNODES) oo[tid] += t;
        __syncthreads();
    }
    if (tid < BNODES) { int e_ = oo[tid] - hh[tid]; oo[tid] = e_; cc[tid] = e_; }
    __syncthreads();

    // ---- scatter into dst-grouped LDS buffer ----
    #pragma unroll
    for (int q = 0; q < 4; ++q) if (valid[q])
        ro[atomicAdd(&cc[((u32)rr[q] >> 16) & (BNODES - 1)], 1)] = rr[q];
    __syncthreads();

    int ovn = *ovf_n_p;
    if (ovn > OVFCAP) ovn = OVFCAP;

    // ---- aggregate + residual + LayerNorm; wave owns nodes wid*8..wid*8+7 ----
    #pragma unroll
    for (int k = 0; k < 8; ++k) {
        int nl = (wid << 3) + k;
        if (nl >= nn) break;
        int beg = oo[nl], end = cc[nl];

        float ax = 0.f, ay = 0.f, az = 0.f, aw = 0.f;
        // 4x unrolled: 4 independent bf16 gather slots in flight per iteration
        for (int p = beg; p < end; p += 16) {
            float at0 = 0.f, at1 = 0.f, at2 = 0.f, at3 = 0.f;
            int s0 = 0, s1i = 0, s2i = 0, s3 = 0;
            int i0 = p + g, i1 = p + 4 + g, i2 = p + 8 + g, i3 = p + 12 + g;
            if (i0 < end) { u64 r2 = ro[i0]; s0  = (u32)r2 & 0xFFFF; at0 = __uint_as_float((u32)(r2 >> 32)); }
            if (i1 < end) { u64 r2 = ro[i1]; s1i = (u32)r2 & 0xFFFF; at1 = __uint_as_float((u32)(r2 >> 32)); }
            if (i2 < end) { u64 r2 = ro[i2]; s2i = (u32)r2 & 0xFFFF; at2 = __uint_as_float((u32)(r2 >> 32)); }
            if (i3 < end) { u64 r2 = ro[i3]; s3  = (u32)r2 & 0xFFFF; at3 = __uint_as_float((u32)(r2 >> 32)); }
            const uint2 v0 = *(const uint2*)(hWb + (size_t)s0  * D + li * 4);
            const uint2 v1 = *(const uint2*)(hWb + (size_t)s1i * D + li * 4);
            const uint2 v2 = *(const uint2*)(hWb + (size_t)s2i * D + li * 4);
            const uint2 v3 = *(const uint2*)(hWb + (size_t)s3  * D + li * 4);
            ax = fmaf(at0, bf_lo(v0.x), ax); ay = fmaf(at0, bf_hi(v0.x), ay);
            az = fmaf(at0, bf_lo(v0.y), az); aw = fmaf(at0, bf_hi(v0.y), aw);
            ax = fmaf(at1, bf_lo(v1.x), ax); ay = fmaf(at1, bf_hi(v1.x), ay);
            az = fmaf(at1, bf_lo(v1.y), az); aw = fmaf(at1, bf_hi(v1.y), aw);
            ax = fmaf(at2, bf_lo(v2.x), ax); ay = fmaf(at2, bf_hi(v2.x), ay);
            az = fmaf(at2, bf_lo(v2.y), az); aw = fmaf(at2, bf_hi(v2.y), aw);
            ax = fmaf(at3, bf_lo(v3.x), ax); ay = fmaf(at3, bf_hi(v3.x), ay);
            az = fmaf(at3, bf_lo(v3.y), az); aw = fmaf(at3, bf_hi(v3.y), aw);
        }

        // overflow safety path (normally ovn == 0); add on group 0 only
        for (int r = 0; r < ovn; ++r) {
            if (ovf_dst[r] != node0 + nl) continue;
            if (g == 0) {
                u32 r2 = ovf_rec[r];
                int s = r2 & 0xFFFF;
                float att = edge_ex(s1[s], s2l[nl]) / denom[s];
                const uint2 v = *(const uint2*)(hWb + (size_t)s * D + li * 4);
                ax = fmaf(att, bf_lo(v.x), ax); ay = fmaf(att, bf_hi(v.x), ay);
                az = fmaf(att, bf_lo(v.y), az); aw = fmaf(att, bf_hi(v.y), aw);
            }
        }

        // reduce across the 4 edge-slot groups
        // NOTE layout change vs fp32 version: (ax,ay,az,aw) are cols
        // (li*4+0 .. li*4+3) exactly as before — bf16 unpack preserves order.
        ax += __shfl_xor(ax, 16, 64); ax += __shfl_xor(ax, 32, 64);
        ay += __shfl_xor(ay, 16, 64); ay += __shfl_xor(ay, 32, 64);
        az += __shfl_xor(az, 16, 64); az += __shfl_xor(az, 32, 64);
        aw += __shfl_xor(aw, 16, 64); aw += __shfl_xor(aw, 32, 64);

        // residual (fp32 path, sequential)
        const float4 hv = *(const float4*)(hW + (size_t)(node0 + nl) * D + li * 4);
        float x0 = hv.x + ax, x1 = hv.y + ay, x2 = hv.z + az, x3 = hv.w + aw;

        // LayerNorm over 64 cols
        float sm = x0 + x1 + x2 + x3;
        sm += __shfl_xor(sm, 1, 64); sm += __shfl_xor(sm, 2, 64);
        sm += __shfl_xor(sm, 4, 64); sm += __shfl_xor(sm, 8, 64);
        float mu = sm * (1.f / D);
        float d0 = x0 - mu, d1 = x1 - mu, d2 = x2 - mu, d3 = x3 - mu;
        float vv = d0 * d0 + d1 * d1 + d2 * d2 + d3 * d3;
        vv += __shfl_xor(vv, 1, 64); vv += __shfl_xor(vv, 2, 64);
        vv += __shfl_xor(vv, 4, 64); vv += __shfl_xor(vv, 8, 64);
        float inv = rsqrtf(vv * (1.f / D) + LN_EPS);

        if (g == 0) {
            const float4 gm = *(const float4*)(gamma + li * 4);
            const float4 bt = *(const float4*)(beta + li * 4);
            float4 o;
            o.x = d0 * inv * gm.x + bt.x;
            o.y = d1 * inv * gm.y + bt.y;
            o.z = d2 * inv * gm.z + bt.z;
            o.w = d3 * inv * gm.w + bt.w;
            *(float4*)(out + (size_t)(node0 + nl) * D + li * 4) = o;
        }
    }
}

// ---------------------------------------------------------------------------
static inline size_t align256(size_t x) { return (x + 255) & ~size_t(255); }

extern "C" void kernel_launch(void* const* d_in, const int* in_sizes, int n_in,
                              void* d_out, int out_size, void* d_ws, size_t ws_size,
                              hipStream_t stream) {
    const float* h    = (const float*)d_in[0];
    const int*   ei   = (const int*)d_in[1];
    const float* W    = (const float*)d_in[2];
    const float* a    = (const float*)d_in[3];
    const float* lng  = (const float*)d_in[4];
    const float* lnb  = (const float*)d_in[5];
    float* out = (float*)d_out;

    const int N = in_sizes[0] / D;
    const int E = in_sizes[1] / 2;
    const int* src = ei;        // edge_index[0]
    const int* dst = ei + E;    // edge_index[1]
    const int nb  = (N + BNODES - 1) >> BSH;   // dst-buckets (64-node)
    const int nsb = (N + 255) >> SSH;          // src-buckets

    // workspace layout
    char* ws = (char*)d_ws;
    size_t off = 0;
    float* hW      = (float*)(ws + off); off += align256(sizeof(float) * (size_t)N * D);
    u16*   hWb     = (u16*)  (ws + off); off += align256(sizeof(u16) * (size_t)N * D);
    float* s1      = (float*)(ws + off); off += align256(sizeof(float) * (size_t)N);
    float* s2      = (float*)(ws + off); off += align256(sizeof(float) * (size_t)N);
    u32*   drecs   = (u32*)  (ws + off); off += align256(sizeof(u32) * (size_t)nb * BCAP);
    u32*   srecs   = (u32*)  (ws + off); off += align256(sizeof(u32) * (size_t)nsb * SCAP);
    u32*   ovf_rec = (u32*)  (ws + off); off += align256(sizeof(u32) * (size_t)OVFCAP);
    int*   ovf_dst = (int*)  (ws + off); off += align256(sizeof(int) * (size_t)OVFCAP);
    // zero-initialized tail: denom, dcnt_g, scnt_g, ovf_n (one memset)
    size_t zero_off = off;
    float* denom   = (float*)(ws + off); off += align256(sizeof(float) * (size_t)N);
    int*   dcnt_g  = (int*)  (ws + off); off += align256(sizeof(int) * (size_t)NBMAX);
    int*   scnt_g  = (int*)  (ws + off); off += align256(sizeof(int) * (size_t)NSBMAX);
    int*   ovf_n   = (int*)  (ws + off); off += align256(sizeof(int));
    size_t zero_bytes = off - zero_off;

    hipMemsetAsync(ws + zero_off, 0, zero_bytes, stream);

    // K1: hW (fp32 + bf16 replica) + attention scores
    k_hw_scores<<<dim3(1024), dim3(256), 0, stream>>>(h, W, a, hW, hWb, s1, s2, N);

    // K2: dual binning (4096 edges/block, 1024 thr)
    k_bin<<<dim3((E + 4095) / 4096), dim3(1024), 0, stream>>>(
        src, dst, s1, s2, denom, dcnt_g, drecs, scnt_g, srecs,
        ovf_rec, ovf_dst, ovf_n, E, nb, nsb);

    // K2b: denom reduction per src-bucket
    k_denom<<<dim3(nsb), dim3(512), 0, stream>>>(srecs, scnt_g, s1, s2, denom, N);

    // K3: fused bucket sort + aggregate (bf16 gathers) + residual + LayerNorm
    k_bucket_agg<<<dim3(nb), dim3(512), 0, stream>>>(
        drecs, dcnt_g, s1, s2, denom, hW, hWb, lng, lnb,
        ovf_rec, ovf_dst, ovf_n, out, N);
}

// Round 14
// 163.788 us; speedup vs baseline: 1.0396x; 1.0030x over previous
//
#include <hip/hip_runtime.h>
#include <hip/hip_bf16.h>

#define NEG_SLOPE 0.2f
#define LN_EPS 1e-5f
#define D 64          // Din == Dout == 64
// NOTE: u32 record packing {src:16|dst:16} requires N <= 65536 (problem: N=50000)
#define BSH 6         // 64 dst-nodes per bucket
#define BNODES 64
#define NBMAX 1024    // dst-buckets (N <= 65536)
#define BCAP 1792     // records per dst-bucket (avg 1280 for N=50k,E=1M; +14 sigma)
#define SSH 8         // 256 srcs per src-bucket
#define NSBMAX 256    // src-buckets (N <= 65536)
#define SCAP 6144     // records per src-bucket (avg 5102; +14 sigma)
#define OVFCAP 65536  // overflow list capacity (safety; normally 0 used)

typedef unsigned long long u64;
typedef unsigned int u32;
typedef unsigned short u16;

// bf16 pack (RNE) / unpack helpers
__device__ __forceinline__ u16 f2bf(float f) {
    u32 u = __float_as_uint(f);
    return (u16)((u + 0x7FFFu + ((u >> 16) & 1u)) >> 16);
}
__device__ __forceinline__ float bf_lo(u32 p) { return __uint_as_float(p << 16); }
__device__ __forceinline__ float bf_hi(u32 p) { return __uint_as_float(p & 0xFFFF0000u); }

// ---------------------------------------------------------------------------
// Kernel 1: hW = h @ W^T  (fp32 + bf16 replica), s1/s2 attention scores.
// Lane j holds W row j in 64 VGPRs; node index readfirstlane'd so h-row
// loads are wave-uniform (scalar pipe); 64 pure FMAs on 4 acc chains.
// ---------------------------------------------------------------------------
__global__ void __launch_bounds__(256, 4)
k_hw_scores(const float* __restrict__ h,
            const float* __restrict__ W,
            const float* __restrict__ a,
            float* __restrict__ hW,
            u16* __restrict__ hWb,
            float* __restrict__ s1,
            float* __restrict__ s2,
            int N) {
    const int lane = threadIdx.x & 63;
    const int wid  = threadIdx.x >> 6;
    const int wavesPerBlock = blockDim.x >> 6;
    const int nWaves = gridDim.x * wavesPerBlock;

    float wcol[D];
    {
        const float4* wr = (const float4*)(W + (size_t)lane * D);
        #pragma unroll
        for (int q = 0; q < D / 4; ++q) {
            float4 w4 = wr[q];
            wcol[q * 4 + 0] = w4.x; wcol[q * 4 + 1] = w4.y;
            wcol[q * 4 + 2] = w4.z; wcol[q * 4 + 3] = w4.w;
        }
    }
    const float a1l = a[lane];
    const float a2l = a[D + lane];

    for (int i = blockIdx.x * wavesPerBlock + wid; i < N; i += nWaves) {
        const int iu = __builtin_amdgcn_readfirstlane(i);
        const float* hr = h + (size_t)iu * D;   // wave-uniform -> scalar loads

        float acc0 = 0.f, acc1 = 0.f, acc2 = 0.f, acc3 = 0.f;
        #pragma unroll
        for (int k = 0; k < D; k += 4) {
            acc0 = fmaf(hr[k + 0], wcol[k + 0], acc0);
            acc1 = fmaf(hr[k + 1], wcol[k + 1], acc1);
            acc2 = fmaf(hr[k + 2], wcol[k + 2], acc2);
            acc3 = fmaf(hr[k + 3], wcol[k + 3], acc3);
        }
        float c = (acc0 + acc1) + (acc2 + acc3);
        hW[(size_t)iu * D + lane] = c;
        hWb[(size_t)iu * D + lane] = f2bf(c);

        float p1 = c * a1l;
        float p2 = c * a2l;
        #pragma unroll
        for (int off = 32; off > 0; off >>= 1) {
            p1 += __shfl_xor(p1, off, 64);
            p2 += __shfl_xor(p2, off, 64);
        }
        if (lane == 0) { s1[iu] = p1; s2[iu] = p2; }
    }
}

__device__ __forceinline__ float edge_ex(float v1, float v2) {
    float x = v1 + v2;
    float e = x > 0.f ? x : NEG_SLOPE * x;
    return expf(fminf(e, 60.f));   // softmax shift-invariant; clamp for safety
}

// ---------------------------------------------------------------------------
// Kernel 2: edge pass, dual binning with LDS SORT before copy-out.
// Old version issued 2M isolated 4-B stores from random lanes (one TCC
// transaction each). Now: records are grouped by bucket in LDS, then
// copied out with consecutive lanes -> consecutive global addresses, so
// each bucket-run coalesces into 1-2 transactions (~4x fewer TCC ops).
//  dst-rec: src | (dstl<<16) | (bucket<<22)   [bucket<1024 fits 10 bits]
//  src-rec: src | (dst<<16)                    [bucket = src>>8 recomputed]
// ---------------------------------------------------------------------------
__global__ void __launch_bounds__(1024)
k_bin(const int* __restrict__ src,
      const int* __restrict__ dst,
      const float* __restrict__ s1,
      const float* __restrict__ s2,
      float* __restrict__ denom,       // only overflow path writes (atomic)
      int* __restrict__ dcnt_g,        // [NBMAX]  (zeroed)
      u32* __restrict__ drecs,         // [nb * BCAP]
      int* __restrict__ scnt_g,        // [NSBMAX] (zeroed)
      u32* __restrict__ srecs,         // [nsb * SCAP]
      u32* __restrict__ ovf_rec,       // [OVFCAP]
      int* __restrict__ ovf_dst,       // [OVFCAP]
      int* __restrict__ ovf_n,         // scalar (zeroed)
      int E, int nb, int nsb) {
    const int TPB = 1024, EPT = 4;     // 4096 edges per block
    __shared__ u32 recbuf[TPB * EPT];                      // 16 KB
    __shared__ int lcnt[NBMAX], lo[NBMAX], cc[NBMAX], lbase[NBMAX]; // 16 KB

    const int tid = threadIdx.x;
    const int chunk = blockIdx.x * (TPB * EPT);
    const int total = min(E - chunk, TPB * EPT);   // valid edges this block

    int sv[EPT], dv[EPT];
    const int e0 = chunk + tid * EPT;
    if (e0 + EPT <= E) {
        int4 s4 = *(const int4*)(src + e0);
        int4 d4 = *(const int4*)(dst + e0);
        sv[0] = s4.x; sv[1] = s4.y; sv[2] = s4.z; sv[3] = s4.w;
        dv[0] = d4.x; dv[1] = d4.y; dv[2] = d4.z; dv[3] = d4.w;
    } else {
        #pragma unroll
        for (int j = 0; j < EPT; ++j) {
            int i = e0 + j;
            sv[j] = (i < E) ? src[i] : 0;
            dv[j] = (i < E) ? dst[i] : -1;
        }
    }

    // ================= PASS 1: dst-binned records =================
    for (int i = tid; i < nb; i += TPB) lcnt[i] = 0;
    __syncthreads();
    #pragma unroll
    for (int j = 0; j < EPT; ++j)
        if (dv[j] >= 0) atomicAdd(&lcnt[dv[j] >> BSH], 1);
    __syncthreads();

    // inclusive scan (nb <= 1024 = TPB: one thread per entry)
    if (tid < nb) lo[tid] = lcnt[tid];
    __syncthreads();
    for (int off = 1; off < nb; off <<= 1) {
        int t = 0;
        if (tid < nb && tid >= off) t = lo[tid - off];
        __syncthreads();
        if (tid < nb) lo[tid] += t;
        __syncthreads();
    }
    if (tid < nb) {
        int e_ = lo[tid] - lcnt[tid];       // exclusive
        lo[tid] = e_; cc[tid] = e_;
        if (lcnt[tid]) lbase[tid] = atomicAdd(&dcnt_g[tid], lcnt[tid]);
    }
    __syncthreads();

    // scatter into bucket-sorted LDS order
    #pragma unroll
    for (int j = 0; j < EPT; ++j) {
        if (dv[j] < 0) continue;
        int b = dv[j] >> BSH;
        u32 rec = (u32)sv[j] | ((u32)(dv[j] & (BNODES - 1)) << 16) | ((u32)b << 22);
        recbuf[atomicAdd(&cc[b], 1)] = rec;
    }
    __syncthreads();

    // coalesced copy-out: consecutive lanes -> consecutive global addrs
    for (int i = tid; i < total; i += TPB) {
        u32 rec = recbuf[i];
        int b = rec >> 22;
        int r = lbase[b] + (i - lo[b]);
        if (r < BCAP) {
            drecs[(size_t)b * BCAP + r] = rec;
        } else {
            int o = atomicAdd(ovf_n, 1);
            if (o < OVFCAP) {
                ovf_rec[o] = rec;
                ovf_dst[o] = (b << BSH) | ((rec >> 16) & (BNODES - 1));
            }
        }
    }
    __syncthreads();

    // ================= PASS 2: src-binned records =================
    for (int i = tid; i < nsb; i += TPB) lcnt[i] = 0;
    __syncthreads();
    #pragma unroll
    for (int j = 0; j < EPT; ++j)
        if (dv[j] >= 0) atomicAdd(&lcnt[sv[j] >> SSH], 1);
    __syncthreads();

    if (tid < nsb) lo[tid] = lcnt[tid];
    __syncthreads();
    for (int off = 1; off < nsb; off <<= 1) {
        int t = 0;
        if (tid < nsb && tid >= off) t = lo[tid - off];
        __syncthreads();
        if (tid < nsb) lo[tid] += t;
        __syncthreads();
    }
    if (tid < nsb) {
        int e_ = lo[tid] - lcnt[tid];
        lo[tid] = e_; cc[tid] = e_;
        if (lcnt[tid]) lbase[tid] = atomicAdd(&scnt_g[tid], lcnt[tid]);
    }
    __syncthreads();

    #pragma unroll
    for (int j = 0; j < EPT; ++j) {
        if (dv[j] < 0) continue;
        int b = sv[j] >> SSH;
        u32 rec = (u32)sv[j] | ((u32)dv[j] << 16);
        recbuf[atomicAdd(&cc[b], 1)] = rec;
    }
    __syncthreads();

    for (int i = tid; i < total; i += TPB) {
        u32 rec = recbuf[i];
        int s = rec & 0xFFFF;
        int b = s >> SSH;
        int r = lbase[b] + (i - lo[b]);
        if (r < SCAP) {
            srecs[(size_t)b * SCAP + r] = rec;
        } else {
            // rare fallback: contribute to denom directly
            atomicAdd(&denom[s], edge_ex(s1[s], s2[rec >> 16]));
        }
    }
}

// ---------------------------------------------------------------------------
// Kernel 2b: denom reduction. One block per src-bucket (256 srcs).
// LDS fp32 accumulation -> single contiguous global write.
// ---------------------------------------------------------------------------
__global__ void __launch_bounds__(512)
k_denom(const u32* __restrict__ srecs,
        const int* __restrict__ scnt_g,
        const float* __restrict__ s1,
        const float* __restrict__ s2,
        float* __restrict__ denom,
        int N) {
    __shared__ float acc[256];
    const int b = blockIdx.x;
    const int tid = threadIdx.x;
    if (tid < 256) acc[tid] = 0.f;
    __syncthreads();

    const int total = min(scnt_g[b], SCAP);
    const u32* base = srecs + (size_t)b * SCAP;
    for (int i = tid; i < total; i += 512) {
        u32 r = base[i];
        int s = r & 0xFFFF;
        int d = r >> 16;
        atomicAdd(&acc[s & 255], edge_ex(s1[s], s2[d]));
    }
    __syncthreads();

    if (tid < 256) {
        int g = (b << SSH) + tid;
        if (g < N) denom[g] += acc[tid];
    }
}

// ---------------------------------------------------------------------------
// Kernel 3: one block (512 thr, 8 waves) per 64-node dst-bucket.
// Stage u32 records, recompute ex, group by local dst in LDS, aggregate
// with 16-edges-in-flight bf16 gathers (8 B/lane), residual + LN (fp32).
// g = lane>>4 (edge slot), li = lane&15 (col/4).
// ---------------------------------------------------------------------------
__global__ void __launch_bounds__(512)
k_bucket_agg(const u32* __restrict__ drecs,
             const int* __restrict__ dcnt_g,
             const float* __restrict__ s1,
             const float* __restrict__ s2,
             const float* __restrict__ denom,
             const float* __restrict__ hW,
             const u16* __restrict__ hWb,
             const float* __restrict__ gamma,
             const float* __restrict__ beta,
             const u32* __restrict__ ovf_rec,
             const int* __restrict__ ovf_dst,
             const int* __restrict__ ovf_n_p,
             float* __restrict__ out,
             int N) {
    __shared__ u64 ro[BCAP];          // {att_bits:32 | rec:32}
    __shared__ float s2l[BNODES];
    __shared__ int hh[BNODES], oo[BNODES], cc[BNODES];

    const int b    = blockIdx.x;
    const int tid  = threadIdx.x;
    const int lane = tid & 63;
    const int wid  = tid >> 6;        // 8 waves
    const int g    = lane >> 4;       // edge-slot group 0..3
    const int li   = lane & 15;       // column quad 0..15
    const int node0 = b << BSH;
    const int nn    = min(BNODES, N - node0);
    const int total = min(dcnt_g[b], BCAP);

    if (tid < nn) s2l[tid] = s2[node0 + tid];
    if (tid < BNODES) hh[tid] = 0;
    __syncthreads();

    // ---- stage + compute att ----
    u64 rr[4]; bool valid[4];
    const u32* base = drecs + (size_t)b * BCAP;
    #pragma unroll
    for (int q = 0; q < 4; ++q) {
        int idx = tid + q * 512;
        valid[q] = idx < total;
        u32 r = valid[q] ? base[idx] : 0u;
        if (valid[q]) {
            int s  = r & 0xFFFF;
            int dl = (r >> 16) & (BNODES - 1);
            float att = edge_ex(s1[s], s2l[dl]) / denom[s];
            rr[q] = ((u64)__float_as_uint(att) << 32) | (u64)r;
            atomicAdd(&hh[dl], 1);
        } else rr[q] = 0;
    }
    __syncthreads();

    // ---- exclusive scan over 64 counters ----
    if (tid < BNODES) oo[tid] = hh[tid];
    __syncthreads();
    for (int off = 1; off < BNODES; off <<= 1) {
        int t = 0;
        if (tid < BNODES && tid >= off) t = oo[tid - off];
        __syncthreads();
        if (tid < BNODES) oo[tid] += t;
        __syncthreads();
    }
    if (tid < BNODES) { int e_ = oo[tid] - hh[tid]; oo[tid] = e_; cc[tid] = e_; }
    __syncthreads();

    // ---- scatter into dst-grouped LDS buffer ----
    #pragma unroll
    for (int q = 0; q < 4; ++q) if (valid[q])
        ro[atomicAdd(&cc[((u32)rr[q] >> 16) & (BNODES - 1)], 1)] = rr[q];
    __syncthreads();

    int ovn = *ovf_n_p;
    if (ovn > OVFCAP) ovn = OVFCAP;

    // ---- aggregate + residual + LayerNorm; wave owns nodes wid*8..wid*8+7 ----
    #pragma unroll
    for (int k = 0; k < 8; ++k) {
        int nl = (wid << 3) + k;
        if (nl >= nn) break;
        int beg = oo[nl], end = cc[nl];

        float ax = 0.f, ay = 0.f, az = 0.f, aw = 0.f;
        // 4x unrolled: 4 independent bf16 gather slots in flight per iteration
        for (int p = beg; p < end; p += 16) {
            float at0 = 0.f, at1 = 0.f, at2 = 0.f, at3 = 0.f;
            int s0 = 0, s1i = 0, s2i = 0, s3 = 0;
            int i0 = p + g, i1 = p + 4 + g, i2 = p + 8 + g, i3 = p + 12 + g;
            if (i0 < end) { u64 r2 = ro[i0]; s0  = (u32)r2 & 0xFFFF; at0 = __uint_as_float((u32)(r2 >> 32)); }
            if (i1 < end) { u64 r2 = ro[i1]; s1i = (u32)r2 & 0xFFFF; at1 = __uint_as_float((u32)(r2 >> 32)); }
            if (i2 < end) { u64 r2 = ro[i2]; s2i = (u32)r2 & 0xFFFF; at2 = __uint_as_float((u32)(r2 >> 32)); }
            if (i3 < end) { u64 r2 = ro[i3]; s3  = (u32)r2 & 0xFFFF; at3 = __uint_as_float((u32)(r2 >> 32)); }
            const uint2 v0 = *(const uint2*)(hWb + (size_t)s0  * D + li * 4);
            const uint2 v1 = *(const uint2*)(hWb + (size_t)s1i * D + li * 4);
            const uint2 v2 = *(const uint2*)(hWb + (size_t)s2i * D + li * 4);
            const uint2 v3 = *(const uint2*)(hWb + (size_t)s3  * D + li * 4);
            ax = fmaf(at0, bf_lo(v0.x), ax); ay = fmaf(at0, bf_hi(v0.x), ay);
            az = fmaf(at0, bf_lo(v0.y), az); aw = fmaf(at0, bf_hi(v0.y), aw);
            ax = fmaf(at1, bf_lo(v1.x), ax); ay = fmaf(at1, bf_hi(v1.x), ay);
            az = fmaf(at1, bf_lo(v1.y), az); aw = fmaf(at1, bf_hi(v1.y), aw);
            ax = fmaf(at2, bf_lo(v2.x), ax); ay = fmaf(at2, bf_hi(v2.x), ay);
            az = fmaf(at2, bf_lo(v2.y), az); aw = fmaf(at2, bf_hi(v2.y), aw);
            ax = fmaf(at3, bf_lo(v3.x), ax); ay = fmaf(at3, bf_hi(v3.x), ay);
            az = fmaf(at3, bf_lo(v3.y), az); aw = fmaf(at3, bf_hi(v3.y), aw);
        }

        // overflow safety path (normally ovn == 0); add on group 0 only
        for (int r = 0; r < ovn; ++r) {
            if (ovf_dst[r] != node0 + nl) continue;
            if (g == 0) {
                u32 r2 = ovf_rec[r];
                int s = r2 & 0xFFFF;
                float att = edge_ex(s1[s], s2l[nl]) / denom[s];
                const uint2 v = *(const uint2*)(hWb + (size_t)s * D + li * 4);
                ax = fmaf(att, bf_lo(v.x), ax); ay = fmaf(att, bf_hi(v.x), ay);
                az = fmaf(att, bf_lo(v.y), az); aw = fmaf(att, bf_hi(v.y), aw);
            }
        }

        // reduce across the 4 edge-slot groups
        ax += __shfl_xor(ax, 16, 64); ax += __shfl_xor(ax, 32, 64);
        ay += __shfl_xor(ay, 16, 64); ay += __shfl_xor(ay, 32, 64);
        az += __shfl_xor(az, 16, 64); az += __shfl_xor(az, 32, 64);
        aw += __shfl_xor(aw, 16, 64); aw += __shfl_xor(aw, 32, 64);

        // residual (fp32 path, sequential)
        const float4 hv = *(const float4*)(hW + (size_t)(node0 + nl) * D + li * 4);
        float x0 = hv.x + ax, x1 = hv.y + ay, x2 = hv.z + az, x3 = hv.w + aw;

        // LayerNorm over 64 cols
        float sm = x0 + x1 + x2 + x3;
        sm += __shfl_xor(sm, 1, 64); sm += __shfl_xor(sm, 2, 64);
        sm += __shfl_xor(sm, 4, 64); sm += __shfl_xor(sm, 8, 64);
        float mu = sm * (1.f / D);
        float d0 = x0 - mu, d1 = x1 - mu, d2 = x2 - mu, d3 = x3 - mu;
        float vv = d0 * d0 + d1 * d1 + d2 * d2 + d3 * d3;
        vv += __shfl_xor(vv, 1, 64); vv += __shfl_xor(vv, 2, 64);
        vv += __shfl_xor(vv, 4, 64); vv += __shfl_xor(vv, 8, 64);
        float inv = rsqrtf(vv * (1.f / D) + LN_EPS);

        if (g == 0) {
            const float4 gm = *(const float4*)(gamma + li * 4);
            const float4 bt = *(const float4*)(beta + li * 4);
            float4 o;
            o.x = d0 * inv * gm.x + bt.x;
            o.y = d1 * inv * gm.y + bt.y;
            o.z = d2 * inv * gm.z + bt.z;
            o.w = d3 * inv * gm.w + bt.w;
            *(float4*)(out + (size_t)(node0 + nl) * D + li * 4) = o;
        }
    }
}

// ---------------------------------------------------------------------------
static inline size_t align256(size_t x) { return (x + 255) & ~size_t(255); }

extern "C" void kernel_launch(void* const* d_in, const int* in_sizes, int n_in,
                              void* d_out, int out_size, void* d_ws, size_t ws_size,
                              hipStream_t stream) {
    const float* h    = (const float*)d_in[0];
    const int*   ei   = (const int*)d_in[1];
    const float* W    = (const float*)d_in[2];
    const float* a    = (const float*)d_in[3];
    const float* lng  = (const float*)d_in[4];
    const float* lnb  = (const float*)d_in[5];
    float* out = (float*)d_out;

    const int N = in_sizes[0] / D;
    const int E = in_sizes[1] / 2;
    const int* src = ei;        // edge_index[0]
    const int* dst = ei + E;    // edge_index[1]
    const int nb  = (N + BNODES - 1) >> BSH;   // dst-buckets (64-node)
    const int nsb = (N + 255) >> SSH;          // src-buckets

    // workspace layout
    char* ws = (char*)d_ws;
    size_t off = 0;
    float* hW      = (float*)(ws + off); off += align256(sizeof(float) * (size_t)N * D);
    u16*   hWb     = (u16*)  (ws + off); off += align256(sizeof(u16) * (size_t)N * D);
    float* s1      = (float*)(ws + off); off += align256(sizeof(float) * (size_t)N);
    float* s2      = (float*)(ws + off); off += align256(sizeof(float) * (size_t)N);
    u32*   drecs   = (u32*)  (ws + off); off += align256(sizeof(u32) * (size_t)nb * BCAP);
    u32*   srecs   = (u32*)  (ws + off); off += align256(sizeof(u32) * (size_t)nsb * SCAP);
    u32*   ovf_rec = (u32*)  (ws + off); off += align256(sizeof(u32) * (size_t)OVFCAP);
    int*   ovf_dst = (int*)  (ws + off); off += align256(sizeof(int) * (size_t)OVFCAP);
    // zero-initialized tail: denom, dcnt_g, scnt_g, ovf_n (one memset)
    size_t zero_off = off;
    float* denom   = (float*)(ws + off); off += align256(sizeof(float) * (size_t)N);
    int*   dcnt_g  = (int*)  (ws + off); off += align256(sizeof(int) * (size_t)NBMAX);
    int*   scnt_g  = (int*)  (ws + off); off += align256(sizeof(int) * (size_t)NSBMAX);
    int*   ovf_n   = (int*)  (ws + off); off += align256(sizeof(int));
    size_t zero_bytes = off - zero_off;

    hipMemsetAsync(ws + zero_off, 0, zero_bytes, stream);

    // K1: hW (fp32 + bf16 replica) + attention scores
    k_hw_scores<<<dim3(1024), dim3(256), 0, stream>>>(h, W, a, hW, hWb, s1, s2, N);

    // K2: dual binning with LDS sort + coalesced copy-out
    k_bin<<<dim3((E + 4095) / 4096), dim3(1024), 0, stream>>>(
        src, dst, s1, s2, denom, dcnt_g, drecs, scnt_g, srecs,
        ovf_rec, ovf_dst, ovf_n, E, nb, nsb);

    // K2b: denom reduction per src-bucket
    k_denom<<<dim3(nsb), dim3(512), 0, stream>>>(srecs, scnt_g, s1, s2, denom, N);

    // K3: fused bucket sort + aggregate (bf16 gathers) + residual + LayerNorm
    k_bucket_agg<<<dim3(nb), dim3(512), 0, stream>>>(
        drecs, dcnt_g, s1, s2, denom, hW, hWb, lng, lnb,
        ovf_rec, ovf_dst, ovf_n, out, N);
}